// Round 3
// baseline (375.057 us; speedup 1.0000x reference)
//
#include <hip/hip_runtime.h>
#include <hip/hip_bf16.h>
#include <math.h>

#define D_MODEL 1024
#define DD (1024 * 1024)

typedef unsigned short ushort_t;
using short8 = __attribute__((ext_vector_type(8))) short;   // 8 bf16 (4 VGPRs)
using f32x4  = __attribute__((ext_vector_type(4))) float;   // 4 fp32 acc
using f32x16 = __attribute__((ext_vector_type(16))) float;  // 16 fp32 acc

#define ACT_NONE 0
#define ACT_SILU 1

__device__ __forceinline__ float bf2f(ushort_t u) {
    return __uint_as_float(((unsigned int)u) << 16);
}
__device__ __forceinline__ ushort_t f2bf(float f) {
    unsigned int x = __float_as_uint(f);
    x += 0x7fffu + ((x >> 16) & 1u);   // round-to-nearest-even
    return (ushort_t)(x >> 16);
}

#define GL2LDS(gp, lp)                                                         \
    __builtin_amdgcn_global_load_lds(                                          \
        (const __attribute__((address_space(1))) void*)(gp),                   \
        (__attribute__((address_space(3))) void*)(lp), 16, 0, 0)

// ---------------------------------------------------------------------------
// 256x256-tile bf16 GEMM, v3: 32x32x16 MFMA + ONE barrier per K-unit.
// 512 threads = 8 waves (2M x 4N), per-wave output 128x64 (4x2 frags of
// 32x32, 16 f32 acc each).  K = 32 units of BK=32; ring of 4 LDS slots.
//
// Per unit u (bank CUR holds unit-u A-frags, NXT receives unit-u+1):
//   t1: vmcnt(4)  [u==NU-2: vmcnt(0)] ; s_barrier
//   t2: SA(u+3); SB(u+3)              [stage into slot (u-1)&3]
//   t3: lgkm(2)   -> afr ks0 + bfr ks0 ready (newest 2 = bfr ks1)
//   t4: 8 MFMA32 ks0
//   t5: RA(u+1) -> NXT [8 ds_read_b128, pinned between t3/t6 asm]
//   t6: lgkm(8)   [last unit: lgkm(0)] -> afr ks1 + bfr ks1 ready
//   t7: 8 MFMA32 ks1
//   t8: RB(u+1) -> bfr [4 ds, pinned after t6 asm]
//
// Safety (in-order DS/vmcnt retirement):
//  - slot WAR: all reads of slot (u-1)&3 are drained by unit u-1's t6
//    lgkm(8) (suffix-of-issue argument), before unit u's t1 barrier.
//  - stage RAW: vmcnt(4)@t1 completes stage(u+1) (only stage(u+2) younger),
//    published by the barrier, read at t5.  u=NU-2 has no younger stage ->
//    vmcnt(0).
//  - C-level LDS reads: compiler's own dependence waits backstop the
//    counted asm waits.
// ---------------------------------------------------------------------------
template <int ACT, int OUTF32, int BIASF>
__global__ __launch_bounds__(512, 2) void gemm256(
    const ushort_t* __restrict__ A,
    const ushort_t* __restrict__ Bt,
    const float* __restrict__ bias,
    void* __restrict__ Cv, int M)
{
    constexpr int K = 1024, N = 1024;
    constexpr int NU = K / 32;                 // 32 K-units
    __shared__ ushort_t lds[4 * 16384];        // 128 KiB: 4 x (A 8192 + B 8192)

    const int tid  = threadIdx.x;
    const int lane = tid & 63;
    const int wave = tid >> 6;                 // 0..7
    const int l31  = lane & 31;
    const int hi   = lane >> 5;                // 0..1
    const int wm   = wave >> 2;                // 0..1  (M-wave)
    const int wn   = wave & 3;                 // 0..3  (N-wave)
    const int bm   = blockIdx.x;
    const int bn   = blockIdx.y;

    const ushort_t* Ab = A  + (size_t)bm * 256 * K;
    const ushort_t* Bb = Bt + (size_t)bn * 256 * K;

    // staging: thread t writes LDS bytes [t*16, t*16+16) (+8192 for row+128)
    const int sg    = (tid & 3) ^ ((tid >> 3) & 3);   // inverse k-chunk swizzle
    const size_t s0 = (size_t)(tid >> 2) * K + (size_t)sg * 8;
    const size_t s1 = s0 + (size_t)128 * K;
    const int d0 = tid * 8;
    const int d1 = tid * 8 + 4096;

    // ds_read offsets (ushort units).  LDS[row][chunk] = glob[row][chunk^x],
    // x = (row>>1)&3.  Frag (ks,hi) wants global chunk ks*2+hi.
    const int x0    = (l31 >> 1) & 3;
    const int c0    = hi ^ x0;                 // ks=0 LDS chunk
    const int arow  = wm * 128 + l31;
    const int brow  = wn * 64 + l31;
    const int aoff0 = arow * 32 + c0 * 8;            // ks=0
    const int aoff1 = arow * 32 + (c0 ^ 2) * 8;      // ks=1
    const int boff0 = brow * 32 + c0 * 8;
    const int boff1 = brow * 32 + (c0 ^ 2) * 8;

    short8 afrX[8], afrY[8], bfr[4];
    f32x16 acc[4][2];
#pragma unroll
    for (int i = 0; i < 4; i++)
#pragma unroll
        for (int j = 0; j < 2; j++)
#pragma unroll
            for (int r = 0; r < 16; r++) acc[i][j][r] = 0.f;

#define SA(v) do { const int b_ = ((v) & 3) * 16384;                           \
        GL2LDS(Ab + s0 + (v) * 32, lds + b_ + d0);                             \
        GL2LDS(Ab + s1 + (v) * 32, lds + b_ + d1); } while (0)
#define SB(v) do { const int b_ = ((v) & 3) * 16384 + 8192;                    \
        GL2LDS(Bb + s0 + (v) * 32, lds + b_ + d0);                             \
        GL2LDS(Bb + s1 + (v) * 32, lds + b_ + d1); } while (0)
// 8 A-frags: [ks*4+mt], ks0 first (lgkm(2) counts on this order)
#define RA_(dst, v) do { const ushort_t* p_ = lds + ((v) & 3) * 16384;         \
        dst[0] = *(const short8*)(p_ + aoff0);                                 \
        dst[1] = *(const short8*)(p_ + aoff0 + 1024);                          \
        dst[2] = *(const short8*)(p_ + aoff0 + 2048);                          \
        dst[3] = *(const short8*)(p_ + aoff0 + 3072);                          \
        dst[4] = *(const short8*)(p_ + aoff1);                                 \
        dst[5] = *(const short8*)(p_ + aoff1 + 1024);                          \
        dst[6] = *(const short8*)(p_ + aoff1 + 2048);                          \
        dst[7] = *(const short8*)(p_ + aoff1 + 3072); } while (0)
// 4 B-frags: [ks*2+nt], ks0 first
#define RB_(v) do { const ushort_t* p_ = lds + ((v) & 3) * 16384 + 8192;       \
        bfr[0] = *(const short8*)(p_ + boff0);                                 \
        bfr[1] = *(const short8*)(p_ + boff0 + 1024);                          \
        bfr[2] = *(const short8*)(p_ + boff1);                                 \
        bfr[3] = *(const short8*)(p_ + boff1 + 1024); } while (0)

#define MFMA8_KS0(CUR) do {                                                    \
        _Pragma("unroll")                                                      \
        for (int mt = 0; mt < 4; mt++) {                                       \
            acc[mt][0] = __builtin_amdgcn_mfma_f32_32x32x16_bf16(              \
                CUR[mt], bfr[0], acc[mt][0], 0, 0, 0);                         \
            acc[mt][1] = __builtin_amdgcn_mfma_f32_32x32x16_bf16(              \
                CUR[mt], bfr[1], acc[mt][1], 0, 0, 0);                         \
        } } while (0)
#define MFMA8_KS1(CUR) do {                                                    \
        _Pragma("unroll")                                                      \
        for (int mt = 0; mt < 4; mt++) {                                       \
            acc[mt][0] = __builtin_amdgcn_mfma_f32_32x32x16_bf16(              \
                CUR[4 + mt], bfr[2], acc[mt][0], 0, 0, 0);                     \
            acc[mt][1] = __builtin_amdgcn_mfma_f32_32x32x16_bf16(              \
                CUR[4 + mt], bfr[3], acc[mt][1], 0, 0, 0);                     \
        } } while (0)

#define UNIT(u, CUR, NXT) do {                                                 \
        if ((u) == NU - 2) asm volatile("s_waitcnt vmcnt(0)" ::: "memory");    \
        else               asm volatile("s_waitcnt vmcnt(4)" ::: "memory");    \
        __builtin_amdgcn_s_barrier();                                          \
        if ((u) + 3 < NU) { SA((u) + 3); SB((u) + 3); }                        \
        asm volatile("s_waitcnt lgkmcnt(2)" ::: "memory");                     \
        __builtin_amdgcn_sched_barrier(0);                                     \
        __builtin_amdgcn_s_setprio(1);                                         \
        MFMA8_KS0(CUR);                                                        \
        __builtin_amdgcn_s_setprio(0);                                         \
        if ((u) + 1 < NU) RA_(NXT, (u) + 1);                                   \
        if ((u) + 1 < NU)                                                      \
            asm volatile("s_waitcnt lgkmcnt(8)" ::: "memory");                 \
        else                                                                   \
            asm volatile("s_waitcnt lgkmcnt(0)" ::: "memory");                 \
        __builtin_amdgcn_sched_barrier(0);                                     \
        __builtin_amdgcn_s_setprio(1);                                         \
        MFMA8_KS1(CUR);                                                        \
        __builtin_amdgcn_s_setprio(0);                                         \
        if ((u) + 1 < NU) RB_((u) + 1);                                        \
    } while (0)

    // prologue: stage units 0,1,2; drain unit 0; load unit-0 frags (bank X)
    SA(0); SB(0);
    SA(1); SB(1);
    SA(2); SB(2);
    asm volatile("s_waitcnt vmcnt(8)" ::: "memory");
    __builtin_amdgcn_s_barrier();
    RA_(afrX, 0);
    RB_(0);

#pragma unroll
    for (int uu = 0; uu < NU; uu += 2) {
        UNIT(uu,     afrX, afrY);
        UNIT(uu + 1, afrY, afrX);
    }
#undef SA
#undef SB
#undef RA_
#undef RB_
#undef MFMA8_KS0
#undef MFMA8_KS1
#undef UNIT

    // epilogue: bias (+SiLU), direct scalar stores.
    // C/D 32x32 layout (m74/m101): col = lane&31,
    // row = (reg&3) + 8*(reg>>2) + 4*(lane>>5)
    float bv[2];
#pragma unroll
    for (int nt = 0; nt < 2; nt++)
        bv[nt] = BIASF ? bias[bn * 256 + wn * 64 + nt * 32 + l31] : 0.f;

#pragma unroll
    for (int mt = 0; mt < 4; mt++) {
#pragma unroll
        for (int nt = 0; nt < 2; nt++) {
            const int col = bn * 256 + wn * 64 + nt * 32 + l31;
#pragma unroll
            for (int r = 0; r < 16; r++) {
                const int row = bm * 256 + wm * 128 + mt * 32 +
                                (r & 3) + 8 * (r >> 2) + 4 * hi;
                float v = acc[mt][nt][r] + bv[nt];
                if (ACT == ACT_SILU) v = v / (1.f + __expf(-v));
                if (OUTF32)
                    ((float*)Cv)[(size_t)row * N + col] = v;
                else
                    ((ushort_t*)Cv)[(size_t)row * N + col] = f2bf(v);
            }
        }
    }
}

// ---------------------------------------------------------------------------
// bf16 GEMM — R2 128x128 structure (kept for the small 1024^3 Wf GEMM and as
// fallback when M % 256 != 0).
// ---------------------------------------------------------------------------
template <int ACT, int OUTF32, int BIASF>
__global__ __launch_bounds__(256) void gemm_bf16(
    const ushort_t* __restrict__ A,
    const ushort_t* __restrict__ Bt,
    const float* __restrict__ bias,
    void* __restrict__ Cv, int M)
{
    constexpr int K = 1024, N = 1024;
    __shared__ ushort_t As[128 * 32];
    __shared__ ushort_t Bs[128 * 32];

    const int tid  = threadIdx.x;
    const int lane = tid & 63;
    const int wave = tid >> 6;
    const int quad = lane >> 4;
    const int lr   = lane & 15;
    const int bm   = blockIdx.x;
    const int bn   = blockIdx.y;
    const int wm   = (wave >> 1) * 64;
    const int wn   = (wave & 1) * 64;

    f32x4 acc[4][4];
#pragma unroll
    for (int i = 0; i < 4; i++)
#pragma unroll
        for (int j = 0; j < 4; j++) acc[i][j] = (f32x4){0.f, 0.f, 0.f, 0.f};

    int ci0 = tid, ci1 = tid + 256;
    int am0 = ci0 >> 2, akc0 = (ci0 & 3) ^ ((am0 >> 1) & 3);
    int am1 = ci1 >> 2, akc1 = (ci1 & 3) ^ ((am1 >> 1) & 3);
    const ushort_t* Ab = A + (size_t)(bm * 128) * K;
    const ushort_t* Bb = Bt + (size_t)(bn * 128) * K;

    for (int k0 = 0; k0 < K; k0 += 32) {
        GL2LDS(Ab + (size_t)am0 * K + k0 + akc0 * 8, As + ci0 * 8);
        GL2LDS(Ab + (size_t)am1 * K + k0 + akc1 * 8, As + ci1 * 8);
        GL2LDS(Bb + (size_t)am0 * K + k0 + akc0 * 8, Bs + ci0 * 8);
        GL2LDS(Bb + (size_t)am1 * K + k0 + akc1 * 8, Bs + ci1 * 8);
        __syncthreads();

        short8 af[4], bfr[4];
#pragma unroll
        for (int t = 0; t < 4; t++) {
            int m = wm + t * 16 + lr;
            af[t] = *(const short8*)(As + m * 32 + ((quad ^ ((m >> 1) & 3)) * 8));
            int n = wn + t * 16 + lr;
            bfr[t] = *(const short8*)(Bs + n * 32 + ((quad ^ ((n >> 1) & 3)) * 8));
        }
#pragma unroll
        for (int mt = 0; mt < 4; mt++)
#pragma unroll
            for (int nt = 0; nt < 4; nt++)
                acc[mt][nt] = __builtin_amdgcn_mfma_f32_16x16x32_bf16(
                    af[mt], bfr[nt], acc[mt][nt], 0, 0, 0);
        __syncthreads();
    }

    float bv[4];
#pragma unroll
    for (int nt = 0; nt < 4; nt++)
        bv[nt] = BIASF ? bias[bn * 128 + wn + nt * 16 + lr] : 0.f;

#pragma unroll
    for (int mt = 0; mt < 4; mt++) {
#pragma unroll
        for (int nt = 0; nt < 4; nt++) {
            const int col = bn * 128 + wn + nt * 16 + lr;
#pragma unroll
            for (int r = 0; r < 4; r++) {
                const int row = bm * 128 + wm + mt * 16 + quad * 4 + r;
                float v = acc[mt][nt][r] + bv[nt];
                if (ACT == ACT_SILU) v = v / (1.f + __expf(-v));
                if (OUTF32)
                    ((float*)Cv)[(size_t)row * N + col] = v;
                else
                    ((ushort_t*)Cv)[(size_t)row * N + col] = f2bf(v);
            }
        }
    }
}

// ---------------------------------------------------------------------------
// In-place LayerNorm over bf16 rows of 1024, fp32 math, eps=1e-5.
// ---------------------------------------------------------------------------
__global__ __launch_bounds__(256) void layernorm_bf16(ushort_t* __restrict__ X)
{
    const int row = blockIdx.x;
    const int tid = threadIdx.x;
    ushort_t* x = X + (size_t)row * D_MODEL + tid * 4;

    uint2 u = *(uint2*)x;
    float a = bf2f(u.x & 0xffff), b = bf2f(u.x >> 16);
    float c = bf2f(u.y & 0xffff), d = bf2f(u.y >> 16);
    float s = a + b + c + d;
    float ss = a * a + b * b + c * c + d * d;

#pragma unroll
    for (int off = 32; off > 0; off >>= 1) {
        s += __shfl_down(s, off);
        ss += __shfl_down(ss, off);
    }
    __shared__ float sbuf[4], ssbuf[4];
    const int wave = tid >> 6;
    if ((tid & 63) == 0) { sbuf[wave] = s; ssbuf[wave] = ss; }
    __syncthreads();
    const float S = sbuf[0] + sbuf[1] + sbuf[2] + sbuf[3];
    const float SS = ssbuf[0] + ssbuf[1] + ssbuf[2] + ssbuf[3];
    const float mu = S * (1.f / D_MODEL);
    const float var = SS * (1.f / D_MODEL) - mu * mu;
    const float r = rsqrtf(var + 1e-5f);

    a = (a - mu) * r; b = (b - mu) * r; c = (c - mu) * r; d = (d - mu) * r;
    u.x = (unsigned)f2bf(a) | ((unsigned)f2bf(b) << 16);
    u.y = (unsigned)f2bf(c) | ((unsigned)f2bf(d) << 16);
    *(uint2*)x = u;
}

// ---------------------------------------------------------------------------
// ONE prep dispatch (flattened 1-D grid), covering:
//  blocks [0, 6144): weight prep, 6 z-slices of 1024 blocks each
//      z=0..4: transpose+convert (wq, mlp0..2, w_out) -> bf16 N-major wt+z*DD
//      z=5:    plain convert W3 -> wt+5*DD
//  blocks [6144, 6144+M*D/2048): x fp32 -> bf16 into Q (8 elems/thread)
//  blocks [last 32): bias_compose: bf[n] = b3 @ Wout + bout, split-K in block
// ---------------------------------------------------------------------------
__global__ __launch_bounds__(256) void prep_all(
    const float* __restrict__ wq, const float* __restrict__ mlp_w,
    const float* __restrict__ w_out, const float* __restrict__ x,
    const float* __restrict__ b3, const float* __restrict__ bout,
    ushort_t* __restrict__ wt, ushort_t* __restrict__ Q,
    float* __restrict__ bf, int nxblk)
{
    const int blk = blockIdx.x;
    const int tid = threadIdx.x;

    if (blk < 6144) {                    // ---- weight prep ----
        const int z = blk >> 10;
        const int t = blk & 1023;        // 32x32 tile index
        const int k0 = (t >> 5) * 32;
        const int n0 = (t & 31) * 32;
        const int r = tid >> 5;          // 0..7
        const int c = tid & 31;          // 0..31

        if (z == 5) {                    // plain convert W3
            const float* src = mlp_w + (size_t)3 * DD;
            ushort_t* dst = wt + (size_t)5 * DD;
#pragma unroll
            for (int i = 0; i < 4; i++) {
                size_t idx = (size_t)(k0 + r + 8 * i) * D_MODEL + n0 + c;
                dst[idx] = f2bf(src[idx]);
            }
            return;
        }
        const float* src = (z == 0) ? wq : (z < 4) ? (mlp_w + (size_t)(z - 1) * DD) : w_out;
        ushort_t* dst = wt + (size_t)z * DD;
        __shared__ float tile[32][33];
#pragma unroll
        for (int i = 0; i < 4; i++)
            tile[r + 8 * i][c] = src[(size_t)(k0 + r + 8 * i) * D_MODEL + n0 + c];
        __syncthreads();
#pragma unroll
        for (int i = 0; i < 4; i++)
            dst[(size_t)(n0 + r + 8 * i) * D_MODEL + k0 + c] = f2bf(tile[c][r + 8 * i]);
        return;
    }
    if (blk < 6144 + nxblk) {            // ---- x -> bf16 ----
        int i = (blk - 6144) * 256 + tid;
        const float4* p = (const float4*)(x + (size_t)i * 8);
        float4 v0 = p[0], v1 = p[1];
        union { ushort_t u[8]; uint4 v; } pk;
        pk.u[0] = f2bf(v0.x); pk.u[1] = f2bf(v0.y);
        pk.u[2] = f2bf(v0.z); pk.u[3] = f2bf(v0.w);
        pk.u[4] = f2bf(v1.x); pk.u[5] = f2bf(v1.y);
        pk.u[6] = f2bf(v1.z); pk.u[7] = f2bf(v1.w);
        *(uint4*)(Q + (size_t)i * 8) = pk.v;
        return;
    }
    // ---- bias_compose: 32 blocks, each 32 n-cols, split-K 8-way ----
    {
        const int b = blk - 6144 - nxblk;        // 0..31
        const int n = b * 32 + (tid & 31);
        const int kg = tid >> 5;                 // 0..7
        float s = 0.f;
        for (int k = kg * 128; k < (kg + 1) * 128; k++)
            s = fmaf(b3[k], w_out[(size_t)k * D_MODEL + n], s);
        __shared__ float red[8][32];
        red[kg][tid & 31] = s;
        __syncthreads();
        if (kg == 0) {
            float t = 0.f;
#pragma unroll
            for (int j = 0; j < 8; j++) t += red[j][tid & 31];
            bf[n] = t + bout[n];
        }
    }
}

// ---------------------------------------------------------------------------
extern "C" void kernel_launch(void* const* d_in, const int* in_sizes, int n_in,
                              void* d_out, int out_size, void* d_ws, size_t ws_size,
                              hipStream_t stream)
{
    const float* x     = (const float*)d_in[0];
    const float* wq    = (const float*)d_in[1];
    const float* bq    = (const float*)d_in[2];
    const float* mlp_w = (const float*)d_in[3];
    const float* mlp_b = (const float*)d_in[4];
    const float* w_out = (const float*)d_in[5];
    const float* b_out = (const float*)d_in[6];

    const int D = D_MODEL;
    const int M = in_sizes[0] / D;   // 16384

    // ws layout (ushort units):
    // wt[0..5)=transposed weights | [5DD,6DD)=W3 plain | [6DD,7DD)=WfT
    // | Q (M*D) | bf (1024 fp32)
    ushort_t* wt  = (ushort_t*)d_ws;
    ushort_t* w3b = wt + (size_t)5 * DD;
    ushort_t* wtF = wt + (size_t)6 * DD;
    ushort_t* Q   = wt + (size_t)7 * DD;
    float*    bf  = (float*)(Q + (size_t)M * D);
    ushort_t* P   = (ushort_t*)d_out;   // bf16 acts alias d_out's fp32 buffer

    // 1. all prep in one dispatch
    const int nxblk = M * D / 2048;     // x-convert blocks (8 elems/thread)
    prep_all<<<6144 + nxblk + 32, 256, 0, stream>>>(
        wq, mlp_w, w_out, x, mlp_b + 3 * D, b_out, wt, Q, bf, nxblk);
    // 2. Wf^T = Wout^T @ W3^T  (N-major rep of Wf = W3*Wout) — small GEMM,
    //    keep 128^2 kernel (64 blocks > 16 blocks of the 256^2 kernel)
    gemm_bf16<ACT_NONE, 0, 0><<<dim3(8, 8), 256, 0, stream>>>(
        wt + (size_t)4 * DD, w3b, nullptr, wtF, 1024);

    if ((M & 255) == 0) {
        dim3 grid(M / 256, D / 256);    // 64 x 4 = 256 blocks = 1/CU
        // 3. q = x @ wq + bq -> P
        gemm256<ACT_NONE, 0, 1><<<grid, 512, 0, stream>>>(Q, wt + (size_t)0 * DD, bq, P, M);
        // 4. LN in place on P
        layernorm_bf16<<<M, 256, 0, stream>>>(P);
        // 5-7. MLP layers 0..2 with SiLU
        gemm256<ACT_SILU, 0, 1><<<grid, 512, 0, stream>>>(P, wt + (size_t)1 * DD, mlp_b + 0 * D, Q, M);
        gemm256<ACT_SILU, 0, 1><<<grid, 512, 0, stream>>>(Q, wt + (size_t)2 * DD, mlp_b + 1 * D, P, M);
        gemm256<ACT_SILU, 0, 1><<<grid, 512, 0, stream>>>(P, wt + (size_t)3 * DD, mlp_b + 2 * D, Q, M);
        // 8. fused (layer3 + out proj): out = h3 @ Wf + bf -> d_out fp32
        gemm256<ACT_NONE, 1, 1><<<grid, 512, 0, stream>>>(Q, wtF, bf, d_out, M);
    } else {
        dim3 grid(M / 128, D / 128);
        gemm_bf16<ACT_NONE, 0, 1><<<grid, 256, 0, stream>>>(Q, wt + (size_t)0 * DD, bq, P, M);
        layernorm_bf16<<<M, 256, 0, stream>>>(P);
        gemm_bf16<ACT_SILU, 0, 1><<<grid, 256, 0, stream>>>(P, wt + (size_t)1 * DD, mlp_b + 0 * D, Q, M);
        gemm_bf16<ACT_SILU, 0, 1><<<grid, 256, 0, stream>>>(Q, wt + (size_t)2 * DD, mlp_b + 1 * D, P, M);
        gemm_bf16<ACT_SILU, 0, 1><<<grid, 256, 0, stream>>>(P, wt + (size_t)3 * DD, mlp_b + 2 * D, Q, M);
        gemm_bf16<ACT_NONE, 1, 1><<<grid, 256, 0, stream>>>(Q, wtF, bf, d_out, M);
    }
}